// Round 3
// baseline (464.298 us; speedup 1.0000x reference)
//
#include <hip/hip_runtime.h>
#include <hip/hip_bf16.h>

// DetectionLoss: YOLO-style 3-layer loss.
// Round 3: the obj gather (4B per 340B-strided cell -> 227 GB/s, latency-bound,
// 110us) replaced by a coalesced float4 full-tensor stream with in-register
// channel filter (137 MB at streaming BW ~ 25us). Obj partials spread over
// 64 banks/layer to avoid same-address atomic serialization at 2093 blocks.
//
// ws float layout: [0..2]=npos, [3..5]=cls_sum, [6..8]=bbox_sum, [9..11]=obj_corr
//                  [20..211] = obj bce0 partial banks (layer*64 + (blk&63))
// ws int layout:   [15]=record count, [16]=done counter,
//                  [256..256+3071]=recIdx, [3328..3328+3071]=recMeta

#define NCLS 80
#define NCH 85
#define REC_IDX_OFF 256
#define REC_META_OFF 3328
#define BANK_OFF 20

// scan partition (float4 counts): p3=6,528,000  p4=1,632,000  p5=408,000
#define CHUNK_F4 4096
#define B3 1594
#define B4 399
#define B5 100
#define SCAN_BLOCKS (B3 + B4 + B5)   // 2093
#define CLS_BLOCKS 240
#define TOT_BLOCKS (SCAN_BLOCKS + CLS_BLOCKS)

__device__ __forceinline__ float bce0f(float x) {
    // BCE(x, target=0) = max(x,0) + log1p(exp(-|x|)); fast-path transcendentals.
    // abs err <= ~1e-7 for |x| where exp(-|x|) underflows log1p linearization.
    return fmaxf(x, 0.0f) + __logf(1.0f + __expf(-fabsf(x)));
}

__device__ __forceinline__ float ciou_loss(float px, float py, float pw, float ph,
                                           float tx, float ty, float tw, float th) {
    float p0 = px - pw * 0.5f, p1 = py - ph * 0.5f, p2 = px + pw * 0.5f, p3 = py + ph * 0.5f;
    float t0 = tx - tw * 0.5f, t1 = ty - th * 0.5f, t2 = tx + tw * 0.5f, t3 = ty + th * 0.5f;
    float ix1 = fmaxf(p0, t0), iy1 = fmaxf(p1, t1);
    float ix2 = fminf(p2, t2), iy2 = fminf(p3, t3);
    float inter = fmaxf(ix2 - ix1, 0.0f) * fmaxf(iy2 - iy1, 0.0f);
    float a1 = (p2 - p0) * (p3 - p1);
    float a2 = (t2 - t0) * (t3 - t1);
    float iou = inter / (a1 + a2 - inter + 1e-7f);
    float pcx = (p0 + p2) * 0.5f, pcy = (p1 + p3) * 0.5f;
    float tcx = (t0 + t2) * 0.5f, tcy = (t1 + t3) * 0.5f;
    float cd = (pcx - tcx) * (pcx - tcx) + (pcy - tcy) * (pcy - tcy);
    float ex1 = fminf(p0, t0), ey1 = fminf(p1, t1);
    float ex2 = fmaxf(p2, t2), ey2 = fmaxf(p3, t3);
    float dd = (ex2 - ex1) * (ex2 - ex1) + (ey2 - ey1) * (ey2 - ey1);
    return 1.0f - (iou - cd / (dd + 1e-7f));
}

// k1: per-box work. One block of 1024 threads (one per (b,m)).
__global__ __launch_bounds__(1024) void k1(
    const float* __restrict__ p3, const float* __restrict__ p4, const float* __restrict__ p5,
    const float* __restrict__ boxes, const int* __restrict__ labels,
    const unsigned char* __restrict__ validb, const float* __restrict__ anchors,
    float* __restrict__ ws)
{
    __shared__ int s_info[3][1024];     // packed: pos<<16 | a<<14 | gy<<7 | gx
    __shared__ float s_acc[12];         // npos[3], cls[3](unused), bbox[3], corr[3]
    __shared__ int s_nrec;
    __shared__ int s_nz[4];
    __shared__ int s_flag;

    int* ws_i = (int*)ws;
    const int t = threadIdx.x;
    if (t < 12) s_acc[t] = 0.0f;
    if (t == 0) s_nrec = 0;
    if (t < 4) s_nz[t] = 0;
    __syncthreads();

    // detect 'valid' storage layout (uint8 / int32 / float32) from byte patterns
    if (t < 256) {
        int nz = 0;
#pragma unroll
        for (int j = 0; j < 4; j++) if (validb[t * 4 + j]) nz |= (1 << j);
        if (nz & 1) atomicOr(&s_nz[0], 1);
        if (nz & 2) atomicOr(&s_nz[1], 1);
        if (nz & 4) atomicOr(&s_nz[2], 1);
        if (nz & 8) atomicOr(&s_nz[3], 1);
    }
    __syncthreads();
    if (t == 0) {
        int f;
        if (!s_nz[1] && !s_nz[2] && !s_nz[3]) f = 0;      // int32
        else if (!s_nz[0] && !s_nz[1]) f = 2;             // float32
        else f = 1;                                        // uint8
        s_flag = f;
    }
    __syncthreads();
    const int flag = s_flag;

    const int b = t >> 6;
    const int m = t & 63;
    const float x1 = boxes[t * 4 + 0], y1 = boxes[t * 4 + 1];
    const float x2 = boxes[t * 4 + 2], y2 = boxes[t * 4 + 3];
    bool valid;
    if (flag == 0)      valid = ((const int*)validb)[t] != 0;
    else if (flag == 1) valid = validb[t] != 0;
    else                valid = ((const float*)validb)[t] != 0.0f;
    const int label = labels[t];

    const int GDIM[3] = {80, 40, 20};
    float cxl[3], cyl[3], wl[3], hl[3];
    int infol[3];
#pragma unroll
    for (int l = 0; l < 3; l++) {
        const float g = (float)GDIM[l];
        const float cx = (x1 + x2) * 0.5f * g;
        const float cy = (y1 + y2) * 0.5f * g;
        const float w = (x2 - x1) * g;
        const float h = (y2 - y1) * g;
        float best = -1.0f; int ba = 0;
#pragma unroll
        for (int a = 0; a < 3; a++) {
            const float aw = anchors[l * 6 + a * 2 + 0];
            const float ah = anchors[l * 6 + a * 2 + 1];
            const float inter = fminf(w, aw) * fminf(h, ah);
            const float uni = w * h + aw * ah - inter;
            const float iou = inter / (uni + 1e-6f);
            if (iou > best) { best = iou; ba = a; }   // jnp.argmax first-max tie-break
        }
        const bool pos = valid && (best > 0.5f);
        int gx = (int)cx; gx = gx < 0 ? 0 : (gx > GDIM[l] - 1 ? GDIM[l] - 1 : gx);
        int gy = (int)cy; gy = gy < 0 ? 0 : (gy > GDIM[l] - 1 ? GDIM[l] - 1 : gy);
        const int info = (pos ? (1 << 16) : 0) | (ba << 14) | (gy << 7) | gx;
        s_info[l][t] = info;
        infol[l] = info; cxl[l] = cx; cyl[l] = cy; wl[l] = w; hl[l] = h;
    }
    __syncthreads();

#pragma unroll
    for (int l = 0; l < 3; l++) {
        const int info = infol[l];
        if (info & (1 << 16)) {
            const int ba = (info >> 14) & 3, gy = (info >> 7) & 127, gx = info & 127;
            const int g = GDIM[l];
            const int idx = (((b * 3 + ba) * g + gy) * g + gx) * NCH;
            const float* base = (l == 0) ? p3 : ((l == 1) ? p4 : p5);
            atomicAdd(&s_acc[l], 1.0f);  // npos
            const float bb = ciou_loss(base[idx + 0], base[idx + 1], base[idx + 2], base[idx + 3],
                                       cxl[l], cyl[l], wl[l], hl[l]);
            atomicAdd(&s_acc[6 + l], bb);
            // dedupe: lowest-m box owning this cell contributes the obj correction
            bool dup = false;
            const int rowbase = b * 64;
            for (int mm = 0; mm < m; mm++) {
                if (s_info[l][rowbase + mm] == info) { dup = true; break; }
            }
            if (!dup) atomicAdd(&s_acc[9 + l], base[idx + 4]);
            const int r = atomicAdd(&s_nrec, 1);
            ws_i[REC_IDX_OFF + r] = idx;
            ws_i[REC_META_OFF + r] = label | (l << 16);
        }
    }
    __syncthreads();

    if (t < 12) ws[t] = s_acc[t];
    if (t == 15) { ws_i[15] = s_nrec; ws_i[16] = 0; }   // record count, done counter
    if (t < 192) ws[BANK_OFF + t] = 0.0f;               // obj partial banks
}

// k2: coalesced obj stream + cls BCE over records + fused finalize.
__global__ __launch_bounds__(256) void k2(
    const float* __restrict__ p3, const float* __restrict__ p4, const float* __restrict__ p5,
    float* __restrict__ ws, float* __restrict__ out)
{
    int* ws_i = (int*)ws;
    const int blk = blockIdx.x, t = threadIdx.x;

    if (blk < SCAN_BLOCKS) {
        // ---- obj: stream one 64KB chunk as float4, filter channel 4 in-register ----
        int layer, base_f4, n_f4;
        const float4* src;
        if (blk < B3)           { layer = 0; src = (const float4*)p3; base_f4 = blk * CHUNK_F4;            n_f4 = 6528000; }
        else if (blk < B3 + B4) { layer = 1; src = (const float4*)p4; base_f4 = (blk - B3) * CHUNK_F4;     n_f4 = 1632000; }
        else                    { layer = 2; src = (const float4*)p5; base_f4 = (blk - B3 - B4) * CHUNK_F4; n_f4 = 408000; }
        float acc = 0.0f;
#pragma unroll 4
        for (int k = 0; k < 16; k++) {
            const int v = base_f4 + k * 256 + t;
            if (v < n_f4) {
                const float4 q = src[v];
                const unsigned r = ((unsigned)v * 4u) % 85u;   // channel of q.x
                if (r - 1u < 4u) {                              // channel 4 is element 4-r
                    const float x = (r == 4u) ? q.x : ((r == 3u) ? q.y : ((r == 2u) ? q.z : q.w));
                    acc += bce0f(x);
                }
            }
        }
#pragma unroll
        for (int off = 32; off > 0; off >>= 1) acc += __shfl_down(acc, off);
        __shared__ float s[4];
        if ((t & 63) == 0) s[t >> 6] = acc;
        __syncthreads();
        if (t == 0) atomicAdd(&ws[BANK_OFF + layer * 64 + (blk & 63)], s[0] + s[1] + s[2] + s[3]);
    } else {
        // ---- cls: BCE over (record, class) jobs ----
        const int P = ws_i[15];
        const int total = P * NCLS;
        float a0 = 0.0f, a1 = 0.0f, a2 = 0.0f;
#pragma unroll
        for (int k = 0; k < 4; k++) {
            const int job = (blk - SCAN_BLOCKS) * 1024 + k * 256 + t;
            if (job < total) {
                const int r = job / NCLS;
                const int c = job - r * NCLS;
                const int idx = ws_i[REC_IDX_OFF + r];
                const int meta = ws_i[REC_META_OFF + r];
                const int l = meta >> 16;
                const int lab = meta & 0xFFFF;
                const float* base = (l == 0) ? p3 : ((l == 1) ? p4 : p5);
                const float logit = base[idx + 5 + c];
                const float tv = (c == lab) ? 1.0f : 0.0f;
                const float bce = fmaxf(logit, 0.0f) - logit * tv + log1pf(expf(-fabsf(logit)));
                a0 += (l == 0) ? bce : 0.0f;
                a1 += (l == 1) ? bce : 0.0f;
                a2 += (l == 2) ? bce : 0.0f;
            }
        }
#pragma unroll
        for (int off = 32; off > 0; off >>= 1) {
            a0 += __shfl_down(a0, off);
            a1 += __shfl_down(a1, off);
            a2 += __shfl_down(a2, off);
        }
        __shared__ float s3[4][3];
        if ((t & 63) == 0) { s3[t >> 6][0] = a0; s3[t >> 6][1] = a1; s3[t >> 6][2] = a2; }
        __syncthreads();
        if (t == 0) {
            const float c0 = s3[0][0] + s3[1][0] + s3[2][0] + s3[3][0];
            const float c1 = s3[0][1] + s3[1][1] + s3[2][1] + s3[3][1];
            const float c2 = s3[0][2] + s3[1][2] + s3[2][2] + s3[3][2];
            if (c0 != 0.0f) atomicAdd(&ws[3], c0);
            if (c1 != 0.0f) atomicAdd(&ws[4], c1);
            if (c2 != 0.0f) atomicAdd(&ws[5], c2);
        }
    }

    // ---- fused finalize: last block to finish combines everything ----
    __threadfence();
    __syncthreads();
    if (t == 0) {
        const int done = atomicAdd(&ws_i[16], 1);
        if (done == TOT_BLOCKS - 1) {
            __threadfence();
            float cls = 0.0f, obj = 0.0f, box = 0.0f;
            const float GRID[3] = {307200.0f, 76800.0f, 19200.0f};
            for (int l = 0; l < 3; l++) {
                const float npos = atomicAdd(&ws[l], 0.0f);
                const float has = npos > 0.0f ? 1.0f : 0.0f;
                const float denom = fmaxf(npos, 1.0f);
                const float clsS = atomicAdd(&ws[3 + l], 0.0f);
                const float boxS = atomicAdd(&ws[6 + l], 0.0f);
                const float corr = atomicAdd(&ws[9 + l], 0.0f);
                float obj0 = 0.0f;
                for (int j = 0; j < 64; j++) obj0 += atomicAdd(&ws[BANK_OFF + l * 64 + j], 0.0f);
                cls += has * clsS / (denom * 80.0f);
                box += has * boxS / denom;
                obj += has * (obj0 - corr) / GRID[l];
            }
            out[0] = 0.5f * cls + 1.0f * obj + 0.05f * box;
        }
    }
}

extern "C" void kernel_launch(void* const* d_in, const int* in_sizes, int n_in,
                              void* d_out, int out_size, void* d_ws, size_t ws_size,
                              hipStream_t stream) {
    const float* p3 = (const float*)d_in[0];
    const float* p4 = (const float*)d_in[1];
    const float* p5 = (const float*)d_in[2];
    const float* boxes = (const float*)d_in[3];
    const int* labels = (const int*)d_in[4];
    const unsigned char* validb = (const unsigned char*)d_in[5];
    const float* anchors = (const float*)d_in[6];
    float* ws = (float*)d_ws;
    float* out = (float*)d_out;

    k1<<<1, 1024, 0, stream>>>(p3, p4, p5, boxes, labels, validb, anchors, ws);
    k2<<<TOT_BLOCKS, 256, 0, stream>>>(p3, p4, p5, ws, out);
}

// Round 4
// 187.700 us; speedup vs baseline: 2.4736x; 2.4736x over previous
//
#include <hip/hip_runtime.h>
#include <hip/hip_bf16.h>

// DetectionLoss: YOLO-style 3-layer loss.
// Round 4: the fused finalize (per-block __threadfence + done-counter) was the
// regression in R2/R3 — device-scope fences cost ~100s of ns/block x 600-2300
// blocks. Revert to fence-free 3-kernel structure (R1's kB measured ~10us with
// the SAME obj gather): k1 per-box, k2 obj+cls blocks with plain atomics,
// k3 tiny finalize. Cross-kernel visibility via stream ordering (R1: absmax 0).
//
// ws float layout: [0..2]=npos, [3..5]=cls_sum, [6..8]=bbox_sum,
//                  [9..11]=obj_corr, [12..14]=obj_bce0_sum
// ws int layout:   [15]=record count,
//                  [256..]=recIdx (3072), [3328..]=recMeta (3072)

#define NCLS 80
#define NCH 85
#define REC_IDX_OFF 256
#define REC_META_OFF 3328
#define OBJ_BLOCKS 394
#define CLS_BLOCKS 240
#define TOT_BLOCKS (OBJ_BLOCKS + CLS_BLOCKS)

__device__ __forceinline__ float bce0(float x) {
    return fmaxf(x, 0.0f) + log1pf(expf(-fabsf(x)));
}

__device__ __forceinline__ float ciou_loss(float px, float py, float pw, float ph,
                                           float tx, float ty, float tw, float th) {
    float p0 = px - pw * 0.5f, p1 = py - ph * 0.5f, p2 = px + pw * 0.5f, p3 = py + ph * 0.5f;
    float t0 = tx - tw * 0.5f, t1 = ty - th * 0.5f, t2 = tx + tw * 0.5f, t3 = ty + th * 0.5f;
    float ix1 = fmaxf(p0, t0), iy1 = fmaxf(p1, t1);
    float ix2 = fminf(p2, t2), iy2 = fminf(p3, t3);
    float inter = fmaxf(ix2 - ix1, 0.0f) * fmaxf(iy2 - iy1, 0.0f);
    float a1 = (p2 - p0) * (p3 - p1);
    float a2 = (t2 - t0) * (t3 - t1);
    float iou = inter / (a1 + a2 - inter + 1e-7f);
    float pcx = (p0 + p2) * 0.5f, pcy = (p1 + p3) * 0.5f;
    float tcx = (t0 + t2) * 0.5f, tcy = (t1 + t3) * 0.5f;
    float cd = (pcx - tcx) * (pcx - tcx) + (pcy - tcy) * (pcy - tcy);
    float ex1 = fminf(p0, t0), ey1 = fminf(p1, t1);
    float ex2 = fmaxf(p2, t2), ey2 = fmaxf(p3, t3);
    float dd = (ex2 - ex1) * (ex2 - ex1) + (ey2 - ey1) * (ey2 - ey1);
    return 1.0f - (iou - cd / (dd + 1e-7f));
}

// k1: per-box work. One block of 1024 threads (one per (b,m)).
__global__ __launch_bounds__(1024) void k1(
    const float* __restrict__ p3, const float* __restrict__ p4, const float* __restrict__ p5,
    const float* __restrict__ boxes, const int* __restrict__ labels,
    const unsigned char* __restrict__ validb, const float* __restrict__ anchors,
    float* __restrict__ ws)
{
    __shared__ int s_info[3][1024];     // packed: pos<<16 | a<<14 | gy<<7 | gx
    __shared__ float s_acc[12];         // npos[3], (unused)[3], bbox[3], corr[3]
    __shared__ int s_nrec;
    __shared__ int s_nz[4];
    __shared__ int s_flag;

    int* ws_i = (int*)ws;
    const int t = threadIdx.x;
    if (t < 12) s_acc[t] = 0.0f;
    if (t == 0) s_nrec = 0;
    if (t < 4) s_nz[t] = 0;
    __syncthreads();

    // detect 'valid' storage layout (uint8 / int32 / float32) from byte patterns
    if (t < 256) {
        int nz = 0;
#pragma unroll
        for (int j = 0; j < 4; j++) if (validb[t * 4 + j]) nz |= (1 << j);
        if (nz & 1) atomicOr(&s_nz[0], 1);
        if (nz & 2) atomicOr(&s_nz[1], 1);
        if (nz & 4) atomicOr(&s_nz[2], 1);
        if (nz & 8) atomicOr(&s_nz[3], 1);
    }
    __syncthreads();
    if (t == 0) {
        int f;
        if (!s_nz[1] && !s_nz[2] && !s_nz[3]) f = 0;      // int32
        else if (!s_nz[0] && !s_nz[1]) f = 2;             // float32
        else f = 1;                                        // uint8
        s_flag = f;
    }
    __syncthreads();
    const int flag = s_flag;

    const int b = t >> 6;
    const int m = t & 63;
    const float x1 = boxes[t * 4 + 0], y1 = boxes[t * 4 + 1];
    const float x2 = boxes[t * 4 + 2], y2 = boxes[t * 4 + 3];
    bool valid;
    if (flag == 0)      valid = ((const int*)validb)[t] != 0;
    else if (flag == 1) valid = validb[t] != 0;
    else                valid = ((const float*)validb)[t] != 0.0f;
    const int label = labels[t];

    const int GDIM[3] = {80, 40, 20};
    float cxl[3], cyl[3], wl[3], hl[3];
    int infol[3];
#pragma unroll
    for (int l = 0; l < 3; l++) {
        const float g = (float)GDIM[l];
        const float cx = (x1 + x2) * 0.5f * g;
        const float cy = (y1 + y2) * 0.5f * g;
        const float w = (x2 - x1) * g;
        const float h = (y2 - y1) * g;
        float best = -1.0f; int ba = 0;
#pragma unroll
        for (int a = 0; a < 3; a++) {
            const float aw = anchors[l * 6 + a * 2 + 0];
            const float ah = anchors[l * 6 + a * 2 + 1];
            const float inter = fminf(w, aw) * fminf(h, ah);
            const float uni = w * h + aw * ah - inter;
            const float iou = inter / (uni + 1e-6f);
            if (iou > best) { best = iou; ba = a; }   // jnp.argmax first-max tie-break
        }
        const bool pos = valid && (best > 0.5f);
        int gx = (int)cx; gx = gx < 0 ? 0 : (gx > GDIM[l] - 1 ? GDIM[l] - 1 : gx);
        int gy = (int)cy; gy = gy < 0 ? 0 : (gy > GDIM[l] - 1 ? GDIM[l] - 1 : gy);
        const int info = (pos ? (1 << 16) : 0) | (ba << 14) | (gy << 7) | gx;
        s_info[l][t] = info;
        infol[l] = info; cxl[l] = cx; cyl[l] = cy; wl[l] = w; hl[l] = h;
    }
    __syncthreads();

#pragma unroll
    for (int l = 0; l < 3; l++) {
        const int info = infol[l];
        if (info & (1 << 16)) {
            const int ba = (info >> 14) & 3, gy = (info >> 7) & 127, gx = info & 127;
            const int g = GDIM[l];
            const int idx = (((b * 3 + ba) * g + gy) * g + gx) * NCH;
            const float* base = (l == 0) ? p3 : ((l == 1) ? p4 : p5);
            atomicAdd(&s_acc[l], 1.0f);  // npos
            const float bb = ciou_loss(base[idx + 0], base[idx + 1], base[idx + 2], base[idx + 3],
                                       cxl[l], cyl[l], wl[l], hl[l]);
            atomicAdd(&s_acc[6 + l], bb);
            // dedupe: lowest-m box owning this cell contributes the obj correction
            bool dup = false;
            const int rowbase = b * 64;
            for (int mm = 0; mm < m; mm++) {
                if (s_info[l][rowbase + mm] == info) { dup = true; break; }
            }
            if (!dup) atomicAdd(&s_acc[9 + l], base[idx + 4]);
            const int r = atomicAdd(&s_nrec, 1);
            ws_i[REC_IDX_OFF + r] = idx;
            ws_i[REC_META_OFF + r] = label | (l << 16);
        }
    }
    __syncthreads();

    if (t < 12) ws[t] = s_acc[t];
    if (t >= 12 && t < 15) ws[t] = 0.0f;   // obj bce0 accumulators
    if (t == 15) ws_i[15] = s_nrec;        // record count
}

// k2: obj gather (BCE(x,0) over obj channel) + cls BCE over records.
// NO fences, NO done counter — plain device atomics only (R1's fast structure).
__global__ __launch_bounds__(256) void k2(
    const float* __restrict__ p3, const float* __restrict__ p4, const float* __restrict__ p5,
    float* __restrict__ ws)
{
    int* ws_i = (int*)ws;
    const int blk = blockIdx.x, t = threadIdx.x;

    if (blk < OBJ_BLOCKS) {
        // ---- obj: sum BCE(x,0) over obj channel of one layer's grid slice ----
        int layer, cell0, ncell;
        const float* base;
        if (blk < 300)      { layer = 0; cell0 = blk * 1024;         ncell = 307200; base = p3; }
        else if (blk < 375) { layer = 1; cell0 = (blk - 300) * 1024; ncell = 76800;  base = p4; }
        else                { layer = 2; cell0 = (blk - 375) * 1024; ncell = 19200;  base = p5; }
        float acc = 0.0f;
#pragma unroll
        for (int k = 0; k < 4; k++) {
            const int cell = cell0 + k * 256 + t;
            if (cell < ncell) acc += bce0(base[(size_t)cell * NCH + 4]);
        }
#pragma unroll
        for (int off = 32; off > 0; off >>= 1) acc += __shfl_down(acc, off);
        __shared__ float s[4];
        if ((t & 63) == 0) s[t >> 6] = acc;
        __syncthreads();
        if (t == 0) atomicAdd(&ws[12 + layer], s[0] + s[1] + s[2] + s[3]);
    } else {
        // ---- cls: BCE over (record, class) jobs ----
        const int P = ws_i[15];
        const int total = P * NCLS;
        float a0 = 0.0f, a1 = 0.0f, a2 = 0.0f;
#pragma unroll
        for (int k = 0; k < 4; k++) {
            const int job = (blk - OBJ_BLOCKS) * 1024 + k * 256 + t;
            if (job < total) {
                const int r = job / NCLS;
                const int c = job - r * NCLS;
                const int idx = ws_i[REC_IDX_OFF + r];
                const int meta = ws_i[REC_META_OFF + r];
                const int l = meta >> 16;
                const int lab = meta & 0xFFFF;
                const float* base = (l == 0) ? p3 : ((l == 1) ? p4 : p5);
                const float logit = base[idx + 5 + c];
                const float tv = (c == lab) ? 1.0f : 0.0f;
                const float bce = fmaxf(logit, 0.0f) - logit * tv + log1pf(expf(-fabsf(logit)));
                a0 += (l == 0) ? bce : 0.0f;
                a1 += (l == 1) ? bce : 0.0f;
                a2 += (l == 2) ? bce : 0.0f;
            }
        }
#pragma unroll
        for (int off = 32; off > 0; off >>= 1) {
            a0 += __shfl_down(a0, off);
            a1 += __shfl_down(a1, off);
            a2 += __shfl_down(a2, off);
        }
        __shared__ float s3[4][3];
        if ((t & 63) == 0) { s3[t >> 6][0] = a0; s3[t >> 6][1] = a1; s3[t >> 6][2] = a2; }
        __syncthreads();
        if (t == 0) {
            const float c0 = s3[0][0] + s3[1][0] + s3[2][0] + s3[3][0];
            const float c1 = s3[0][1] + s3[1][1] + s3[2][1] + s3[3][1];
            const float c2 = s3[0][2] + s3[1][2] + s3[2][2] + s3[3][2];
            if (c0 != 0.0f) atomicAdd(&ws[3], c0);
            if (c1 != 0.0f) atomicAdd(&ws[4], c1);
            if (c2 != 0.0f) atomicAdd(&ws[5], c2);
        }
    }
}

// k3: finalize (1 thread). Stream ordering guarantees k2's atomics are visible.
__global__ void k3(const float* __restrict__ ws, float* __restrict__ out) {
    float cls = 0.0f, obj = 0.0f, box = 0.0f;
    const float GRID[3] = {307200.0f, 76800.0f, 19200.0f};
    for (int l = 0; l < 3; l++) {
        const float npos = ws[l];
        const float has = npos > 0.0f ? 1.0f : 0.0f;
        const float denom = fmaxf(npos, 1.0f);
        cls += has * ws[3 + l] / (denom * 80.0f);
        box += has * ws[6 + l] / denom;
        obj += has * (ws[12 + l] - ws[9 + l]) / GRID[l];
    }
    out[0] = 0.5f * cls + 1.0f * obj + 0.05f * box;
}

extern "C" void kernel_launch(void* const* d_in, const int* in_sizes, int n_in,
                              void* d_out, int out_size, void* d_ws, size_t ws_size,
                              hipStream_t stream) {
    const float* p3 = (const float*)d_in[0];
    const float* p4 = (const float*)d_in[1];
    const float* p5 = (const float*)d_in[2];
    const float* boxes = (const float*)d_in[3];
    const int* labels = (const int*)d_in[4];
    const unsigned char* validb = (const unsigned char*)d_in[5];
    const float* anchors = (const float*)d_in[6];
    float* ws = (float*)d_ws;
    float* out = (float*)d_out;

    k1<<<1, 1024, 0, stream>>>(p3, p4, p5, boxes, labels, validb, anchors, ws);
    k2<<<TOT_BLOCKS, 256, 0, stream>>>(p3, p4, p5, ws);
    k3<<<1, 1, 0, stream>>>(ws, out);
}

// Round 5
// 183.711 us; speedup vs baseline: 2.5273x; 1.0217x over previous
//
#include <hip/hip_runtime.h>
#include <hip/hip_bf16.h>

// DetectionLoss: YOLO-style 3-layer loss.
// Round 5: k1 merged into the big kernel. The record-list dependency is gone:
// cls jobs use a STATIC mapping (3072 potential records x 80 classes = 245,760
// jobs = 240x1024) and recompute positivity (~30 VALU) per job. Per-box work
// (npos/CIoU/obj-corr+dedupe) rides along as 4 blocks that rebuild the full
// info table in LDS. Every block writes its own private partial slot
// unconditionally -> NO global atomics, NO zero-init, poison-safe.
// Fixed harness overhead ~155us (d_ws 418MB re-poison fill = 65us of it);
// controllable part was ~33us (k1+k2+k3+3 gaps), now ~17us (K+k3+2 gaps).
//
// ws float layout:
//   [bblk*16 + 0..8]   box-block partials (npos[3], bbox[3], corr[3]), bblk<4
//   [64 + i]           obj partials, i<788 (i<600 -> L0, <750 -> L1, else L2)
//   [1024 + cblk*3+l]  cls partials, cblk<240

#define NCLS 80
#define NCH 85
#define OBJ_BLOCKS 788     // 600 + 150 + 38, 512 cells each
#define CLS_BLOCKS 240     // 240*1024 == 3072*80 jobs exactly
#define BOX_BLOCKS 4
#define TOT_BLOCKS (OBJ_BLOCKS + CLS_BLOCKS + BOX_BLOCKS)
#define OBJ_PART_OFF 64
#define CLS_PART_OFF 1024

__device__ __forceinline__ float bce0(float x) {
    return fmaxf(x, 0.0f) + log1pf(expf(-fabsf(x)));
}

__device__ __forceinline__ float ciou_loss(float px, float py, float pw, float ph,
                                           float tx, float ty, float tw, float th) {
    float p0 = px - pw * 0.5f, p1 = py - ph * 0.5f, p2 = px + pw * 0.5f, p3 = py + ph * 0.5f;
    float t0 = tx - tw * 0.5f, t1 = ty - th * 0.5f, t2 = tx + tw * 0.5f, t3 = ty + th * 0.5f;
    float ix1 = fmaxf(p0, t0), iy1 = fmaxf(p1, t1);
    float ix2 = fminf(p2, t2), iy2 = fminf(p3, t3);
    float inter = fmaxf(ix2 - ix1, 0.0f) * fmaxf(iy2 - iy1, 0.0f);
    float a1 = (p2 - p0) * (p3 - p1);
    float a2 = (t2 - t0) * (t3 - t1);
    float iou = inter / (a1 + a2 - inter + 1e-7f);
    float pcx = (p0 + p2) * 0.5f, pcy = (p1 + p3) * 0.5f;
    float tcx = (t0 + t2) * 0.5f, tcy = (t1 + t3) * 0.5f;
    float cd = (pcx - tcx) * (pcx - tcx) + (pcy - tcy) * (pcy - tcy);
    float ex1 = fminf(p0, t0), ey1 = fminf(p1, t1);
    float ex2 = fmaxf(p2, t2), ey2 = fmaxf(p3, t3);
    float dd = (ex2 - ex1) * (ex2 - ex1) + (ey2 - ey1) * (ey2 - ey1);
    return 1.0f - (iou - cd / (dd + 1e-7f));
}

// detect 'valid' storage layout (uint8 / int32 / float32) from byte patterns.
// 256 threads scan the 1024-byte window; returns 0=int32, 1=uint8, 2=float32.
__device__ __forceinline__ int detect_valid_flag(const unsigned char* validb, int t,
                                                 int* s_nz, int* s_flag) {
    if (t < 4) s_nz[t] = 0;
    __syncthreads();
    {
        int nz = 0;
#pragma unroll
        for (int j = 0; j < 4; j++) if (validb[t * 4 + j]) nz |= (1 << j);
        if (nz & 1) atomicOr(&s_nz[0], 1);
        if (nz & 2) atomicOr(&s_nz[1], 1);
        if (nz & 4) atomicOr(&s_nz[2], 1);
        if (nz & 8) atomicOr(&s_nz[3], 1);
    }
    __syncthreads();
    if (t == 0) {
        int f;
        if (!s_nz[1] && !s_nz[2] && !s_nz[3]) f = 0;      // int32
        else if (!s_nz[0] && !s_nz[1]) f = 2;             // float32
        else f = 1;                                        // uint8
        *s_flag = f;
    }
    __syncthreads();
    return *s_flag;
}

__device__ __forceinline__ bool read_valid(const unsigned char* validb, int bm, int flag) {
    if (flag == 0) return ((const int*)validb)[bm] != 0;
    if (flag == 1) return validb[bm] != 0;
    return ((const float*)validb)[bm] != 0.0f;
}

// anchor match for box bm at layer l: returns pos, best anchor, cell, cx/cy/w/h
__device__ __forceinline__ void match_box(
    const float* __restrict__ boxes, const float* __restrict__ anchors,
    bool valid, int bm, int l, int gdim,
    bool& pos, int& ba, int& gx, int& gy,
    float& cx, float& cy, float& w, float& h)
{
    const float x1 = boxes[bm * 4 + 0], y1 = boxes[bm * 4 + 1];
    const float x2 = boxes[bm * 4 + 2], y2 = boxes[bm * 4 + 3];
    const float g = (float)gdim;
    cx = (x1 + x2) * 0.5f * g;
    cy = (y1 + y2) * 0.5f * g;
    w = (x2 - x1) * g;
    h = (y2 - y1) * g;
    float best = -1.0f; ba = 0;
#pragma unroll
    for (int a = 0; a < 3; a++) {
        const float aw = anchors[l * 6 + a * 2 + 0];
        const float ah = anchors[l * 6 + a * 2 + 1];
        const float inter = fminf(w, aw) * fminf(h, ah);
        const float uni = w * h + aw * ah - inter;
        const float iou = inter / (uni + 1e-6f);
        if (iou > best) { best = iou; ba = a; }   // jnp.argmax first-max tie-break
    }
    pos = valid && (best > 0.5f);
    gx = (int)cx; gx = gx < 0 ? 0 : (gx > gdim - 1 ? gdim - 1 : gx);
    gy = (int)cy; gy = gy < 0 ? 0 : (gy > gdim - 1 ? gdim - 1 : gy);
}

__global__ __launch_bounds__(256) void K(
    const float* __restrict__ p3, const float* __restrict__ p4, const float* __restrict__ p5,
    const float* __restrict__ boxes, const int* __restrict__ labels,
    const unsigned char* __restrict__ validb, const float* __restrict__ anchors,
    float* __restrict__ ws)
{
    const int blk = blockIdx.x, t = threadIdx.x;
    const int GDIM[3] = {80, 40, 20};

    if (blk < OBJ_BLOCKS) {
        // ---- obj: sum BCE(x,0) over obj channel, 512 cells per block ----
        int layer, cell0, ncell;
        const float* base;
        if (blk < 600)      { layer = 0; cell0 = blk * 512;         ncell = 307200; base = p3; }
        else if (blk < 750) { layer = 1; cell0 = (blk - 600) * 512; ncell = 76800;  base = p4; }
        else                { layer = 2; cell0 = (blk - 750) * 512; ncell = 19200;  base = p5; }
        float acc = 0.0f;
#pragma unroll
        for (int k = 0; k < 2; k++) {
            const int cell = cell0 + k * 256 + t;
            if (cell < ncell) acc += bce0(base[(size_t)cell * NCH + 4]);
        }
#pragma unroll
        for (int off = 32; off > 0; off >>= 1) acc += __shfl_down(acc, off);
        __shared__ float s[4];
        if ((t & 63) == 0) s[t >> 6] = acc;
        __syncthreads();
        if (t == 0) ws[OBJ_PART_OFF + blk] = s[0] + s[1] + s[2] + s[3];
    } else if (blk < OBJ_BLOCKS + CLS_BLOCKS) {
        // ---- cls: static job mapping, recompute positivity per job ----
        __shared__ int s_nz[4], s_flag;
        const int flag = detect_valid_flag(validb, t, s_nz, &s_flag);
        const int cblk = blk - OBJ_BLOCKS;
        float a0 = 0.0f, a1 = 0.0f, a2 = 0.0f;
#pragma unroll
        for (int k = 0; k < 4; k++) {
            const int job = cblk * 1024 + k * 256 + t;   // < 245760 always
            const int rec = job / NCLS;
            const int c = job - rec * NCLS;
            const int bm = rec / 3;
            const int l = rec - bm * 3;
            const bool valid = read_valid(validb, bm, flag);
            bool pos; int ba, gx, gy; float cx, cy, w, h;
            match_box(boxes, anchors, valid, bm, l, GDIM[l], pos, ba, gx, gy, cx, cy, w, h);
            if (pos) {
                const int b = bm >> 6;
                const int g = GDIM[l];
                const int idx = (((b * 3 + ba) * g + gy) * g + gx) * NCH;
                const float* base = (l == 0) ? p3 : ((l == 1) ? p4 : p5);
                const float logit = base[idx + 5 + c];
                const float tv = (c == labels[bm]) ? 1.0f : 0.0f;
                const float bce = fmaxf(logit, 0.0f) - logit * tv + log1pf(expf(-fabsf(logit)));
                a0 += (l == 0) ? bce : 0.0f;
                a1 += (l == 1) ? bce : 0.0f;
                a2 += (l == 2) ? bce : 0.0f;
            }
        }
#pragma unroll
        for (int off = 32; off > 0; off >>= 1) {
            a0 += __shfl_down(a0, off);
            a1 += __shfl_down(a1, off);
            a2 += __shfl_down(a2, off);
        }
        __shared__ float s3[4][3];
        if ((t & 63) == 0) { s3[t >> 6][0] = a0; s3[t >> 6][1] = a1; s3[t >> 6][2] = a2; }
        __syncthreads();
        if (t == 0) {
            ws[CLS_PART_OFF + cblk * 3 + 0] = s3[0][0] + s3[1][0] + s3[2][0] + s3[3][0];
            ws[CLS_PART_OFF + cblk * 3 + 1] = s3[0][1] + s3[1][1] + s3[2][1] + s3[3][1];
            ws[CLS_PART_OFF + cblk * 3 + 2] = s3[0][2] + s3[1][2] + s3[2][2] + s3[3][2];
        }
    } else {
        // ---- box: npos / CIoU / obj-corr with dedupe, 256 boxes per block ----
        __shared__ int s_nz[4], s_flag;
        __shared__ int s_info[3][1024];   // packed: pos<<16 | a<<14 | gy<<7 | gx
        __shared__ float s_bacc[9];       // npos[3], bbox[3], corr[3]
        const int flag = detect_valid_flag(validb, t, s_nz, &s_flag);
        if (t < 9) s_bacc[t] = 0.0f;
        // phase 1: full info table (all 1024 boxes x 3 layers) for global dedupe
#pragma unroll
        for (int j = 0; j < 4; j++) {
            const int bm = t + j * 256;
            const bool valid = read_valid(validb, bm, flag);
#pragma unroll
            for (int l = 0; l < 3; l++) {
                bool pos; int ba, gx, gy; float cx, cy, w, h;
                match_box(boxes, anchors, valid, bm, l, GDIM[l], pos, ba, gx, gy, cx, cy, w, h);
                s_info[l][bm] = (pos ? (1 << 16) : 0) | (ba << 14) | (gy << 7) | gx;
            }
        }
        __syncthreads();
        // phase 2: this block's 256-box slice
        const int bblk = blk - OBJ_BLOCKS - CLS_BLOCKS;
        const int bm = bblk * 256 + t;
        const int b = bm >> 6;
        const int m = bm & 63;
        const bool valid = read_valid(validb, bm, flag);
#pragma unroll
        for (int l = 0; l < 3; l++) {
            const int info = s_info[l][bm];
            if (info & (1 << 16)) {
                const int ba = (info >> 14) & 3, gy = (info >> 7) & 127, gx = info & 127;
                const int g = GDIM[l];
                const int idx = (((b * 3 + ba) * g + gy) * g + gx) * NCH;
                const float* base = (l == 0) ? p3 : ((l == 1) ? p4 : p5);
                bool pos; int ba2, gx2, gy2; float cx, cy, w, h;
                match_box(boxes, anchors, valid, bm, l, GDIM[l], pos, ba2, gx2, gy2, cx, cy, w, h);
                atomicAdd(&s_bacc[0 + l], 1.0f);
                const float bb = ciou_loss(base[idx + 0], base[idx + 1], base[idx + 2], base[idx + 3],
                                           cx, cy, w, h);
                atomicAdd(&s_bacc[3 + l], bb);
                // dedupe: lowest-m box (global order) owning this cell adds the correction
                bool dup = false;
                const int rowbase = b * 64;
                for (int mm = rowbase; mm < rowbase + m; mm++) {
                    if (s_info[l][mm] == info) { dup = true; break; }
                }
                if (!dup) atomicAdd(&s_bacc[6 + l], base[idx + 4]);
            }
        }
        __syncthreads();
        if (t < 9) ws[bblk * 16 + t] = s_bacc[t];
    }
}

// k3: 256-thread finalize. Sums private partial slots; no atomics anywhere else.
__global__ __launch_bounds__(256) void k3(const float* __restrict__ ws, float* __restrict__ out) {
    __shared__ float s_acc[16];  // [0..2]npos [3..5]bbox [6..8]corr [9..11]obj [12..14]cls
    const int t = threadIdx.x;
    if (t < 16) s_acc[t] = 0.0f;
    __syncthreads();
    for (int i = t; i < OBJ_BLOCKS; i += 256) {
        const int l = (i < 600) ? 0 : ((i < 750) ? 1 : 2);
        atomicAdd(&s_acc[9 + l], ws[OBJ_PART_OFF + i]);
    }
    for (int i = t; i < CLS_BLOCKS * 3; i += 256) {
        atomicAdd(&s_acc[12 + i % 3], ws[CLS_PART_OFF + i]);
    }
    if (t < BOX_BLOCKS * 9) {
        const int bblk = t / 9, r = t % 9;
        atomicAdd(&s_acc[r], ws[bblk * 16 + r]);
    }
    __syncthreads();
    if (t == 0) {
        float cls = 0.0f, obj = 0.0f, box = 0.0f;
        const float GRID[3] = {307200.0f, 76800.0f, 19200.0f};
        for (int l = 0; l < 3; l++) {
            const float npos = s_acc[l];
            const float has = npos > 0.0f ? 1.0f : 0.0f;
            const float denom = fmaxf(npos, 1.0f);
            cls += has * s_acc[12 + l] / (denom * 80.0f);
            box += has * s_acc[3 + l] / denom;
            obj += has * (s_acc[9 + l] - s_acc[6 + l]) / GRID[l];
        }
        out[0] = 0.5f * cls + 1.0f * obj + 0.05f * box;
    }
}

extern "C" void kernel_launch(void* const* d_in, const int* in_sizes, int n_in,
                              void* d_out, int out_size, void* d_ws, size_t ws_size,
                              hipStream_t stream) {
    const float* p3 = (const float*)d_in[0];
    const float* p4 = (const float*)d_in[1];
    const float* p5 = (const float*)d_in[2];
    const float* boxes = (const float*)d_in[3];
    const int* labels = (const int*)d_in[4];
    const unsigned char* validb = (const unsigned char*)d_in[5];
    const float* anchors = (const float*)d_in[6];
    float* ws = (float*)d_ws;
    float* out = (float*)d_out;

    K<<<TOT_BLOCKS, 256, 0, stream>>>(p3, p4, p5, boxes, labels, validb, anchors, ws);
    k3<<<1, 256, 0, stream>>>(ws, out);
}